// Round 11
// baseline (228.743 us; speedup 1.0000x reference)
//
#include <hip/hip_runtime.h>
#include <hip/hip_bf16.h>
#include <math.h>

// B=4, N=256, F=1024, H=16, K=128, HID=4096, TAB=32, D=64
typedef __hip_bfloat16 bf16;
typedef float f32x4 __attribute__((ext_vector_type(4)));
typedef short bf16x8 __attribute__((ext_vector_type(8)));

#define AS1 __attribute__((address_space(1)))
#define AS3 __attribute__((address_space(3)))

#define ASM_VMCNT4 asm volatile("s_waitcnt vmcnt(4)" ::: "memory")
#define ASM_VMCNT0 asm volatile("s_waitcnt vmcnt(0)" ::: "memory")
#define ASM_LGKM0  asm volatile("s_waitcnt lgkmcnt(0)" ::: "memory")
#define ASM_BARRIER asm volatile("s_barrier" ::: "memory")

// ---------------- setup: cvt nfeat->bf16 | pack qkv bias | TW table
__global__ __launch_bounds__(256) void setup_kernel(
    const float* __restrict__ nfeat, bf16* __restrict__ nfeatb,
    const float* __restrict__ bq, const float* __restrict__ bk,
    const float* __restrict__ bv, float* __restrict__ bqkv,
    const float* __restrict__ table, const float* __restrict__ w1,
    float* __restrict__ tw)
{
    int bid = blockIdx.x, t = threadIdx.x;
    if (bid < 1024) {
        int i = (bid * 256 + t) * 4;
        float4 v = *reinterpret_cast<const float4*>(nfeat + i);
        nfeatb[i + 0] = (bf16)v.x; nfeatb[i + 1] = (bf16)v.y;
        nfeatb[i + 2] = (bf16)v.z; nfeatb[i + 3] = (bf16)v.w;
    } else if (bid < 1036) {
        int i = (bid - 1024) * 256 + t;
        bqkv[i] = i < 1024 ? bq[i] : (i < 2048 ? bk[i - 1024] : bv[i - 2048]);
    } else {
        #pragma unroll
        for (int e = t; e < 512; e += 256) {
            int r = e >> 4, o = e & 15;
            float a = 0.f;
            for (int k = 0; k < 128; ++k) a += table[r * 128 + k] * w1[k * 16 + o];
            tw[e] = a;
        }
    }
}

// ---------------- fast transpose+convert: all weights, 64x64 tiles, vectorized.
__global__ __launch_bounds__(256) void wtx_kernel(
    const float* __restrict__ wq, const float* __restrict__ wk,
    const float* __restrict__ wv, const float* __restrict__ wo,
    const float* __restrict__ fw1, const float* __restrict__ fw2,
    bf16* __restrict__ qkvT, bf16* __restrict__ woT,
    bf16* __restrict__ fw1T, bf16* __restrict__ fw2T)
{
    __shared__ float tile[64][68];
    int bid = blockIdx.x, t = threadIdx.x;
    const float* W; bf16* WT; int Kd, Nd, local;
    if (bid < 768)       { int ws = bid >> 8; local = bid & 255;
                           W = ws == 0 ? wq : ws == 1 ? wk : wv;
                           WT = qkvT + ws * 1048576; Kd = 1024; Nd = 1024; }
    else if (bid < 1024) { local = bid - 768;  W = wo;  WT = woT;  Kd = 1024; Nd = 1024; }
    else if (bid < 2048) { local = bid - 1024; W = fw1; WT = fw1T; Kd = 1024; Nd = 4096; }
    else                 { local = bid - 2048; W = fw2; WT = fw2T; Kd = 4096; Nd = 1024; }
    int ntn = Nd >> 6;
    int k0 = (local / ntn) * 64, n0 = (local % ntn) * 64;

    {
        int k = t >> 2, nb = (t & 3) * 16;
        const float* src = W + (size_t)(k0 + k) * Nd + n0 + nb;
        #pragma unroll
        for (int c = 0; c < 4; c++) {
            float4 v = *reinterpret_cast<const float4*>(src + c * 4);
            *reinterpret_cast<float4*>(&tile[k][nb + c * 4]) = v;
        }
    }
    __syncthreads();

    {
        int w = t >> 6, l = t & 63;
        int n = w * 16 + (l >> 2), kb = (l & 3) * 16;
        bf16x8 o0, o1;
        #pragma unroll
        for (int j = 0; j < 8; j++) {
            union { bf16 b; short s; } u;
            u.b = (bf16)tile[kb + j][n];
            o0[j] = u.s;
        }
        #pragma unroll
        for (int j = 0; j < 8; j++) {
            union { bf16 b; short s; } u;
            u.b = (bf16)tile[kb + 8 + j][n];
            o1[j] = u.s;
        }
        bf16* dst = WT + (size_t)(n0 + n) * Kd + k0 + kb;
        *reinterpret_cast<bf16x8*>(dst) = o0;
        *reinterpret_cast<bf16x8*>(dst + 8) = o1;
    }
}

// ---------------- encoder: writes attn_bias TRANSPOSED as [B,H,N,N], bf16
__global__ __launch_bounds__(256) void enc_kernel(
    const int* __restrict__ sp, const float* __restrict__ rd,
    const float* __restrict__ tw,
    const float* __restrict__ means, const float* __restrict__ stds,
    const float* __restrict__ gmul, const float* __restrict__ gbias,
    const float* __restrict__ w1, const float* __restrict__ b1,
    const float* __restrict__ w2, const float* __restrict__ b2,
    bf16* __restrict__ biasT)
{
    __shared__ float w1s[128][16];
    __shared__ float w2s[16][16];
    __shared__ float b1s[16], b2s[16];
    __shared__ float meanS[128], istdS[128], coefS[128];
    int t = threadIdx.x;
    for (int i = t; i < 2048; i += 256) w1s[i >> 4][i & 15] = w1[2048 + i];
    w2s[t >> 4][t & 15] = w2[t];
    if (t < 16) { b1s[t] = b1[t]; b2s[t] = b2[t]; }
    if (t < 128) {
        float s = fabsf(stds[t]) + 0.01f;
        meanS[t] = means[t];
        istdS[t] = 1.f / s;
        coefS[t] = 1.f / (sqrtf(2.f * 3.14159f) * s);
    }
    __syncthreads();

    int p = blockIdx.x * 256 + t;
    int idx = sp[p];
    float xv = gmul[0] * rd[p] + gbias[0];

    float acc[16];
    #pragma unroll
    for (int o = 0; o < 16; o++) acc[o] = b1s[o] + tw[idx * 16 + o];

    for (int k = 0; k < 128; k++) {
        float d = (xv - meanS[k]) * istdS[k];
        float g = coefS[k] * __expf(-0.5f * d * d);
        #pragma unroll
        for (int o = 0; o < 16; o++) acc[o] += g * w1s[k][o];
    }
    float h[16];
    #pragma unroll
    for (int o = 0; o < 16; o++) {
        float a = acc[o];
        h[o] = 0.5f * a * (1.f + erff(a * 0.70710678118f));
    }
    float outv[16];
    #pragma unroll
    for (int o = 0; o < 16; o++) outv[o] = b2s[o];
    #pragma unroll
    for (int q = 0; q < 16; q++) {
        float hq = h[q];
        #pragma unroll
        for (int o = 0; o < 16; o++) outv[o] += hq * w2s[q][o];
    }
    int b = blockIdx.x >> 8, i = blockIdx.x & 255;
    #pragma unroll
    for (int hh = 0; hh < 16; hh++)
        biasT[(((b * 16 + hh) * 256 + i) << 8) + t] = (bf16)outv[hh];
}

// ---------------- kgemm (r9 structure): 64x64 tile, BK=64, 4 waves, triple-buf.
// epi: 2=relu(+bias) bf16 ; 3=QKV scatter bf16: q*8 | k [B,H,N,D], v^T [B,H,D,N]
__global__ __launch_bounds__(256, 3) void kgemm(
    const bf16* __restrict__ A, const bf16* __restrict__ BT,
    const float* __restrict__ bias, void* __restrict__ C,
    int M, int Nd, int Kd, int epi)
{
    __shared__ __align__(16) char smem[49152];
    int t = threadIdx.x;
    int w = t >> 6, l = t & 63;
    int wr = w >> 1, wc = w & 1;
    int lr = l & 15, hi = l >> 4;
    int row0 = blockIdx.y * 64, col0 = blockIdx.x * 64;

    f32x4 acc[2][2];
    #pragma unroll
    for (int i = 0; i < 2; i++)
        #pragma unroll
        for (int j = 0; j < 2; j++) acc[i][j] = (f32x4){0.f, 0.f, 0.f, 0.f};

    const bf16* Asrc = A + (size_t)(row0 + (t & 63)) * Kd + (t >> 6) * 8;
    const bf16* Bsrc = BT + (size_t)(col0 + (t & 63)) * Kd + (t >> 6) * 8;
    int wbase = (t & 192) * 16;

    #pragma unroll
    for (int p = 0; p < 2; p++) {
        __builtin_amdgcn_global_load_lds((const AS1 void*)(Asrc + p * 32),
                                         (AS3 void*)(smem + p * 4096 + wbase), 16, 0, 0);
        __builtin_amdgcn_global_load_lds((const AS1 void*)(Bsrc + p * 32),
                                         (AS3 void*)(smem + 8192 + p * 4096 + wbase), 16, 0, 0);
    }
    #pragma unroll
    for (int p = 0; p < 2; p++) {
        __builtin_amdgcn_global_load_lds((const AS1 void*)(Asrc + 64 + p * 32),
                                         (AS3 void*)(smem + 16384 + p * 4096 + wbase), 16, 0, 0);
        __builtin_amdgcn_global_load_lds((const AS1 void*)(Bsrc + 64 + p * 32),
                                         (AS3 void*)(smem + 16384 + 8192 + p * 4096 + wbase), 16, 0, 0);
    }

    int nsteps = Kd >> 6;
    int cur = 0;
    for (int s = 0; s < nsteps; ++s) {
        if (s + 1 < nsteps) { ASM_VMCNT4; }
        else               { ASM_VMCNT0; }
        ASM_BARRIER;

        if (s + 2 < nsteps) {
            const bf16* An = Asrc + (s + 2) * 64;
            const bf16* Bn = Bsrc + (s + 2) * 64;
            int nb = cur + 2; if (nb >= 3) nb -= 3;
            char* dst = smem + nb * 16384;
            #pragma unroll
            for (int p = 0; p < 2; p++) {
                __builtin_amdgcn_global_load_lds((const AS1 void*)(An + p * 32),
                    (AS3 void*)(dst + p * 4096 + wbase), 16, 0, 0);
                __builtin_amdgcn_global_load_lds((const AS1 void*)(Bn + p * 32),
                    (AS3 void*)(dst + 8192 + p * 4096 + wbase), 16, 0, 0);
            }
        }

        const char* base = smem + cur * 16384;
        bf16x8 af[2][2], bfr[2][2];
        #pragma unroll
        for (int kk = 0; kk < 2; kk++) {
            #pragma unroll
            for (int mi = 0; mi < 2; mi++)
                af[kk][mi] = *(const bf16x8*)(base + kk * 4096 + hi * 1024 +
                                              (wr * 32 + mi * 16 + lr) * 16);
            #pragma unroll
            for (int nj = 0; nj < 2; nj++)
                bfr[kk][nj] = *(const bf16x8*)(base + 8192 + kk * 4096 + hi * 1024 +
                                               (wc * 32 + nj * 16 + lr) * 16);
        }
        ASM_LGKM0;
        __builtin_amdgcn_sched_barrier(0);
        __builtin_amdgcn_s_setprio(1);
        #pragma unroll
        for (int kk = 0; kk < 2; kk++)
            #pragma unroll
            for (int mi = 0; mi < 2; mi++)
                #pragma unroll
                for (int nj = 0; nj < 2; nj++)
                    acc[mi][nj] = __builtin_amdgcn_mfma_f32_16x16x32_bf16(
                        af[kk][mi], bfr[kk][nj], acc[mi][nj], 0, 0, 0);
        __builtin_amdgcn_s_setprio(0);
        cur = cur + 1; if (cur >= 3) cur = 0;
    }

    #pragma unroll
    for (int i = 0; i < 2; i++) {
        int rb = row0 + wr * 32 + i * 16 + hi * 4;
        #pragma unroll
        for (int j = 0; j < 2; j++) {
            int cc = col0 + wc * 32 + j * 16 + lr;
            float bsv = bias[cc];
            f32x4 v = acc[i][j];
            #pragma unroll
            for (int q = 0; q < 4; q++) {
                int r = rb + q;
                float x = v[q] + bsv;
                if (epi == 2) {
                    ((bf16*)C)[(size_t)r * Nd + cc] = (bf16)fmaxf(x, 0.f);
                } else {
                    bf16* Cb = (bf16*)C;
                    int sel = cc >> 10, ccc = cc & 1023;
                    int hh = ccc >> 6, dd = ccc & 63;
                    int bb = r >> 8, ii = r & 255;
                    if (sel == 0)
                        Cb[(((bb * 16 + hh) * 256 + ii) << 6) + dd] = (bf16)(x * 8.0f);
                    else if (sel == 1)
                        Cb[1048576 + (((bb * 16 + hh) * 256 + ii) << 6) + dd] = (bf16)x;
                    else
                        Cb[2097152 + ((((bb * 16 + hh) << 6) + dd) << 8) + ii] = (bf16)x;
                }
            }
        }
    }
}

// ---------------- wgemm: wave-autonomous GEMM. 1 wave/block, 32x32 tile, BK=32,
// ZERO barriers: the wave stages its own tiles (global_load_lds, depth-2,
// counted vmcnt) and self-paces. Split-K via blockIdx.z -> f32 partials.
__global__ __launch_bounds__(64, 8) void wgemm(
    const bf16* __restrict__ A, const bf16* __restrict__ BT,
    float* __restrict__ P, int M, int Nd, int Kd)
{
    __shared__ __align__(16) char smem[8192];    // 2 bufs x (A 2KB | B 2KB)
    int l = threadIdx.x;
    int lr = l & 15, hi = l >> 4;
    int row0 = blockIdx.y * 32, col0 = blockIdx.x * 32;
    int klen = Kd / gridDim.z, kbeg = blockIdx.z * klen;

    f32x4 acc[2][2];
    #pragma unroll
    for (int i = 0; i < 2; i++)
        #pragma unroll
        for (int j = 0; j < 2; j++) acc[i][j] = (f32x4){0.f, 0.f, 0.f, 0.f};

    // staging: inst p covers 16B unit u=p*64+l -> k-octet c=u>>5, row r=u&31,
    // LDS addr u*16 (linear = wave base + lane*16 with base p*1024).
    const bf16* Asrc = A + (size_t)(row0 + (l & 31)) * Kd + kbeg + (l >> 5) * 8;
    const bf16* Bsrc = BT + (size_t)(col0 + (l & 31)) * Kd + kbeg + (l >> 5) * 8;

    #define WSTAGE(ss, buf)                                                     \
        _Pragma("unroll")                                                       \
        for (int p = 0; p < 2; p++) {                                           \
            __builtin_amdgcn_global_load_lds((const AS1 void*)(Asrc + (ss) * 32 + p * 16), \
                (AS3 void*)(smem + (buf) * 4096 + p * 1024), 16, 0, 0);         \
            __builtin_amdgcn_global_load_lds((const AS1 void*)(Bsrc + (ss) * 32 + p * 16), \
                (AS3 void*)(smem + (buf) * 4096 + 2048 + p * 1024), 16, 0, 0);  \
        }

    WSTAGE(0, 0);
    WSTAGE(1, 1);

    int nsteps = klen >> 5;
    for (int s = 0; s < nsteps; ++s) {
        int bufc = s & 1;
        if (s + 1 < nsteps) { ASM_VMCNT4; }      // tile s's 4 landed; s+1 in flight
        else               { ASM_VMCNT0; }
        const char* bb = smem + bufc * 4096;
        bf16x8 af[2], bfr[2];
        #pragma unroll
        for (int mi = 0; mi < 2; mi++)
            af[mi] = *(const bf16x8*)(bb + (hi * 32 + mi * 16 + lr) * 16);
        #pragma unroll
        for (int nj = 0; nj < 2; nj++)
            bfr[nj] = *(const bf16x8*)(bb + 2048 + (hi * 32 + nj * 16 + lr) * 16);
        ASM_LGKM0;                               // frags in regs
        __builtin_amdgcn_sched_barrier(0);       // rule #18
        if (s + 2 < nsteps) { WSTAGE(s + 2, bufc); }   // safe: reads done
        #pragma unroll
        for (int mi = 0; mi < 2; mi++)
            #pragma unroll
            for (int nj = 0; nj < 2; nj++)
                acc[mi][nj] = __builtin_amdgcn_mfma_f32_16x16x32_bf16(
                    af[mi], bfr[nj], acc[mi][nj], 0, 0, 0);
    }
    #undef WSTAGE

    float* Pz = P + (size_t)blockIdx.z * M * Nd;
    #pragma unroll
    for (int mi = 0; mi < 2; mi++) {
        int rb = row0 + mi * 16 + hi * 4;
        #pragma unroll
        for (int nj = 0; nj < 2; nj++) {
            int cc = col0 + nj * 16 + lr;
            f32x4 v = acc[mi][nj];
            #pragma unroll
            for (int q = 0; q < 4; q++) Pz[(size_t)(rb + q) * Nd + cc] = v[q];
        }
    }
}

// ---------------- fused attention (unchanged)
__global__ __launch_bounds__(256) void flash_kernel(
    const bf16* __restrict__ Qb, const bf16* __restrict__ Kb,
    const bf16* __restrict__ VT, const bf16* __restrict__ biasT,
    bf16* __restrict__ out)
{
    __shared__ __align__(16) char pls[32768];
    int t = threadIdx.x;
    int w = t >> 6, l = t & 63;
    int lr = l & 15, hi = l >> 4;
    int bh = blockIdx.x >> 2, iq = blockIdx.x & 3;
    int b = bh >> 4, h = bh & 15;
    int i0 = iq * 64 + w * 16;

    const bf16* Qp = Qb + (bh * 256 + i0 + lr) * 64 + hi * 8;
    bf16x8 qf0 = *(const bf16x8*)(Qp);
    bf16x8 qf1 = *(const bf16x8*)(Qp + 32);

    f32x4 acc[16];
    #pragma unroll
    for (int f = 0; f < 16; f++) acc[f] = (f32x4){0.f, 0.f, 0.f, 0.f};

    const bf16* Kp = Kb + (bh * 256 + lr) * 64 + hi * 8;
    #pragma unroll
    for (int f = 0; f < 16; f++) {
        bf16x8 kf0 = *(const bf16x8*)(Kp + f * 1024);
        bf16x8 kf1 = *(const bf16x8*)(Kp + f * 1024 + 32);
        acc[f] = __builtin_amdgcn_mfma_f32_16x16x32_bf16(qf0, kf0, acc[f], 0, 0, 0);
        acc[f] = __builtin_amdgcn_mfma_f32_16x16x32_bf16(qf1, kf1, acc[f], 0, 0, 0);
    }

    const bf16* bp = biasT + (bh * 256 + i0 + hi * 4) * 256 + lr;
    #pragma unroll
    for (int f = 0; f < 16; f++)
        #pragma unroll
        for (int q = 0; q < 4; q++)
            acc[f][q] += __bfloat162float(bp[q * 256 + f * 16]);

    float inv[4];
    #pragma unroll
    for (int q = 0; q < 4; q++) {
        float m = acc[0][q];
        #pragma unroll
        for (int f = 1; f < 16; f++) m = fmaxf(m, acc[f][q]);
        #pragma unroll
        for (int msk = 1; msk < 16; msk <<= 1) m = fmaxf(m, __shfl_xor(m, msk));
        float s = 0.f;
        #pragma unroll
        for (int f = 0; f < 16; f++) {
            float e = __expf(acc[f][q] - m);
            acc[f][q] = e;
            s += e;
        }
        #pragma unroll
        for (int msk = 1; msk < 16; msk <<= 1) s += __shfl_xor(s, msk);
        inv[q] = 1.f / s;
    }

    char* Pw = pls + w * 8192;
    #pragma unroll
    for (int f = 0; f < 16; f++) {
        int j = f * 16 + lr;
        int c = j >> 3, jo = j & 7;
        #pragma unroll
        for (int q = 0; q < 4; q++)
            *(bf16*)(Pw + c * 256 + (hi * 4 + q) * 16 + jo * 2) = (bf16)(acc[f][q] * inv[q]);
    }
    __syncthreads();

    const char* Pr = pls + w * 8192 + hi * 256 + lr * 16;
    const bf16* Vp = VT + (bh * 64 + lr) * 256 + hi * 8;
    #pragma unroll
    for (int n = 0; n < 4; n++) {
        f32x4 o = (f32x4){0.f, 0.f, 0.f, 0.f};
        #pragma unroll
        for (int ks = 0; ks < 8; ks++) {
            bf16x8 pa = *(const bf16x8*)(Pr + ks * 1024);
            bf16x8 vb = *(const bf16x8*)(Vp + n * 4096 + ks * 32);
            o = __builtin_amdgcn_mfma_f32_16x16x32_bf16(pa, vb, o, 0, 0, 0);
        }
        #pragma unroll
        for (int q = 0; q < 4; q++)
            out[(b * 256 + i0 + hi * 4 + q) * 1024 + h * 64 + n * 16 + lr] = (bf16)o[q];
    }
}

// ---------------- LN( add + bias + sum_s part[s] ), f32 out + optional bf16 out
__global__ __launch_bounds__(256) void ln_fused_kernel(
    const float* __restrict__ part, int S,
    const float* __restrict__ bias, const float* __restrict__ add,
    const float* __restrict__ g, const float* __restrict__ bta,
    float* __restrict__ out, bf16* __restrict__ ob)
{
    int row = blockIdx.x;
    int t = threadIdx.x;
    float v[4];
    float sum = 0.f;
    #pragma unroll
    for (int i = 0; i < 4; i++) {
        int c = t + i * 256;
        float x = add[row * 1024 + c] + bias[c];
        for (int s = 0; s < S; s++) x += part[s * 1048576 + row * 1024 + c];
        v[i] = x;
        sum += x;
    }
    __shared__ float red[8];
    #pragma unroll
    for (int off = 32; off; off >>= 1) sum += __shfl_xor(sum, off);
    if ((t & 63) == 0) red[t >> 6] = sum;
    __syncthreads();
    float mean = (red[0] + red[1] + red[2] + red[3]) * (1.f / 1024.f);
    float vs = 0.f;
    #pragma unroll
    for (int i = 0; i < 4; i++) { float d = v[i] - mean; vs += d * d; }
    #pragma unroll
    for (int off = 32; off; off >>= 1) vs += __shfl_xor(vs, off);
    if ((t & 63) == 0) red[4 + (t >> 6)] = vs;
    __syncthreads();
    float var = (red[4] + red[5] + red[6] + red[7]) * (1.f / 1024.f);
    float invs = rsqrtf(var + 1e-5f);
    #pragma unroll
    for (int i = 0; i < 4; i++) {
        int c = t + i * 256;
        float o = (v[i] - mean) * invs * g[c] + bta[c];
        out[row * 1024 + c] = o;
        if (ob) ob[row * 1024 + c] = (bf16)o;
    }
}

extern "C" void kernel_launch(void* const* d_in, const int* in_sizes, int n_in,
                              void* d_out, int out_size, void* d_ws, size_t ws_size,
                              hipStream_t stream)
{
    const float* nfeat  = (const float*)d_in[0];
    const int*   sp     = (const int*)  d_in[1];
    const float* rd     = (const float*)d_in[2];
    const float* table  = (const float*)d_in[3];
    const float* gmeans = (const float*)d_in[4];
    const float* gstds  = (const float*)d_in[5];
    const float* gmul   = (const float*)d_in[6];
    const float* gbias  = (const float*)d_in[7];
    const float* w1     = (const float*)d_in[8];
    const float* b1     = (const float*)d_in[9];
    const float* w2     = (const float*)d_in[10];
    const float* b2     = (const float*)d_in[11];
    const float* wq     = (const float*)d_in[12];
    const float* bq     = (const float*)d_in[13];
    const float* wk     = (const float*)d_in[14];
    const float* bk     = (const float*)d_in[15];
    const float* wv     = (const float*)d_in[16];
    const float* bv     = (const float*)d_in[17];
    const float* wo     = (const float*)d_in[18];
    const float* bo     = (const float*)d_in[19];
    const float* fw1    = (const float*)d_in[20];
    const float* fb1    = (const float*)d_in[21];
    const float* fw2    = (const float*)d_in[22];
    const float* fb2    = (const float*)d_in[23];
    const float* ln1g   = (const float*)d_in[24];
    const float* ln1b   = (const float*)d_in[25];
    const float* ln2g   = (const float*)d_in[26];
    const float* ln2b   = (const float*)d_in[27];

    const size_t MB = 1 << 20;
    char* cws = (char*)d_ws;
    bf16*  biasT   = (bf16*)(cws);             // 0-8MB; reused as hiddenb post-flash
    bf16*  qkvb    = (bf16*)(cws + 8 * MB);    // 8-14MB: q | k [B,H,N,D], v^T [B,H,D,N]
    float* part    = (float*)(cws + 16 * MB);  // 16-48MB: split-K partials (S<=4)
    bf16*  qkvT    = (bf16*)(cws + 48 * MB);   // 48-54MB
    bf16*  woT     = (bf16*)(cws + 54 * MB);   // 54-56MB
    bf16*  fw1T    = (bf16*)(cws + 56 * MB);   // 56-64MB
    bf16*  fw2T    = (bf16*)(cws + 64 * MB);   // 64-72MB
    float* x1      = (float*)(cws + 72 * MB);  // 72-76MB
    bf16*  nfeatb  = (bf16*)(cws + 76 * MB);   // 76-78MB
    bf16*  x1b     = (bf16*)(cws + 78 * MB);   // 78-80MB
    bf16*  attnob  = (bf16*)(cws + 80 * MB);   // 80-82MB
    float* bqkv    = (float*)(cws + 82 * MB);  // 12KB
    float* tw      = (float*)(cws + 82 * MB + 16384);
    bf16*  hiddenb = biasT;                    // [1024][4096] bf16 (after flash)

    setup_kernel<<<1037, 256, 0, stream>>>(nfeat, nfeatb, bq, bk, bv, bqkv,
                                           table, w1, tw);
    wtx_kernel<<<3072, 256, 0, stream>>>(wq, wk, wv, wo, fw1, fw2,
                                         qkvT, woT, fw1T, fw2T);
    enc_kernel<<<1024, 256, 0, stream>>>(sp, rd, tw, gmeans, gstds, gmul, gbias,
                                         w1, b1, w2, b2, biasT);

    // QKV fused GEMM -> bf16 q/k/v^T (direct epilogue, 768 blocks)
    kgemm<<<dim3(48, 16), 256, 0, stream>>>(nfeatb, qkvT, bqkv, qkvb,
                                            1024, 3072, 1024, 3);

    flash_kernel<<<256, 256, 0, stream>>>(qkvb, qkvb + 1048576, qkvb + 2097152,
                                          biasT, attnob);

    // Wo: wave-autonomous split-K=4 (4096 one-wave blocks) -> partials ; LN1 folds
    wgemm<<<dim3(32, 32, 4), 64, 0, stream>>>(attnob, woT, part, 1024, 1024, 1024);
    ln_fused_kernel<<<1024, 256, 0, stream>>>(part, 4, bo, nfeat, ln1g, ln1b, x1, x1b);

    // FFN1: kgemm direct (1024 blocks), ReLU -> bf16 hidden
    kgemm<<<dim3(64, 16), 256, 0, stream>>>(x1b, fw1T, fb1, hiddenb,
                                            1024, 4096, 1024, 2);

    // FFN2: wave-autonomous split-K=4 (4096 one-wave blocks) -> partials ; LN2 -> d_out
    wgemm<<<dim3(32, 32, 4), 64, 0, stream>>>(hiddenb, fw2T, part, 1024, 1024, 4096);
    ln_fused_kernel<<<1024, 256, 0, stream>>>(part, 4, fb2, x1, ln2g, ln2b,
                                              (float*)d_out, nullptr);
}

// Round 12
// 188.244 us; speedup vs baseline: 1.2151x; 1.2151x over previous
//
#include <hip/hip_runtime.h>
#include <hip/hip_bf16.h>
#include <math.h>

// B=4, N=256, F=1024, H=16, K=128, HID=4096, TAB=32, D=64
typedef __hip_bfloat16 bf16;
typedef float f32x4 __attribute__((ext_vector_type(4)));
typedef short bf16x8 __attribute__((ext_vector_type(8)));

#define AS1 __attribute__((address_space(1)))
#define AS3 __attribute__((address_space(3)))

// ---------------- front: wtx (0..3071) | enc (3072..4095) | setup (4096..5132)
__global__ __launch_bounds__(256) void front_kernel(
    const float* __restrict__ wq, const float* __restrict__ wk,
    const float* __restrict__ wv, const float* __restrict__ wo,
    const float* __restrict__ fw1, const float* __restrict__ fw2,
    bf16* __restrict__ qkvT, bf16* __restrict__ woT,
    bf16* __restrict__ fw1T, bf16* __restrict__ fw2T,
    const int* __restrict__ sp, const float* __restrict__ rd,
    const float* __restrict__ tw,
    const float* __restrict__ means, const float* __restrict__ stds,
    const float* __restrict__ gmul, const float* __restrict__ gbias,
    const float* __restrict__ w1, const float* __restrict__ b1,
    const float* __restrict__ w2, const float* __restrict__ b2,
    bf16* __restrict__ biasT,
    const float* __restrict__ nfeat, bf16* __restrict__ nfeatb,
    const float* __restrict__ bq, const float* __restrict__ bk,
    const float* __restrict__ bv, float* __restrict__ bqkv)
{
    __shared__ __align__(16) char smraw[17408];
    int bid = blockIdx.x, t = threadIdx.x;

    if (bid < 3072) {
        // ---- weight transpose+convert, 64x64 tiles, vectorized
        float (*tile)[68] = (float(*)[68])smraw;
        const float* W; bf16* WT; int Kd, Nd, local;
        if (bid < 768)       { int ws = bid >> 8; local = bid & 255;
                               W = ws == 0 ? wq : ws == 1 ? wk : wv;
                               WT = qkvT + ws * 1048576; Kd = 1024; Nd = 1024; }
        else if (bid < 1024) { local = bid - 768;  W = wo;  WT = woT;  Kd = 1024; Nd = 1024; }
        else if (bid < 2048) { local = bid - 1024; W = fw1; WT = fw1T; Kd = 1024; Nd = 4096; }
        else                 { local = bid - 2048; W = fw2; WT = fw2T; Kd = 4096; Nd = 1024; }
        int ntn = Nd >> 6;
        int k0 = (local / ntn) * 64, n0 = (local % ntn) * 64;
        {
            int k = t >> 2, nb = (t & 3) * 16;
            const float* src = W + (size_t)(k0 + k) * Nd + n0 + nb;
            #pragma unroll
            for (int c = 0; c < 4; c++) {
                float4 v = *reinterpret_cast<const float4*>(src + c * 4);
                *reinterpret_cast<float4*>(&tile[k][nb + c * 4]) = v;
            }
        }
        __syncthreads();
        {
            int w = t >> 6, l = t & 63;
            int n = w * 16 + (l >> 2), kb = (l & 3) * 16;
            bf16x8 o0, o1;
            #pragma unroll
            for (int j = 0; j < 8; j++) {
                union { bf16 b; short s; } u;
                u.b = (bf16)tile[kb + j][n];
                o0[j] = u.s;
            }
            #pragma unroll
            for (int j = 0; j < 8; j++) {
                union { bf16 b; short s; } u;
                u.b = (bf16)tile[kb + 8 + j][n];
                o1[j] = u.s;
            }
            bf16* dst = WT + (size_t)(n0 + n) * Kd + k0 + kb;
            *reinterpret_cast<bf16x8*>(dst) = o0;
            *reinterpret_cast<bf16x8*>(dst + 8) = o1;
        }
        return;
    }

    if (bid < 4096) {
        // ---- encoder: attn_bias transposed [B,H,N,N] bf16
        int ebid = bid - 3072;
        struct EncSm {
            float w1s[128][16];
            float w2s[16][16];
            float b1s[16], b2s[16];
            float meanS[128], istdS[128], coefS[128];
        };
        EncSm& sm = *(EncSm*)smraw;
        for (int i = t; i < 2048; i += 256) sm.w1s[i >> 4][i & 15] = w1[2048 + i];
        sm.w2s[t >> 4][t & 15] = w2[t];
        if (t < 16) { sm.b1s[t] = b1[t]; sm.b2s[t] = b2[t]; }
        if (t < 128) {
            float s = fabsf(stds[t]) + 0.01f;
            sm.meanS[t] = means[t];
            sm.istdS[t] = 1.f / s;
            sm.coefS[t] = 1.f / (sqrtf(2.f * 3.14159f) * s);
        }
        __syncthreads();

        int p = ebid * 256 + t;
        int idx = sp[p];
        float xv = gmul[0] * rd[p] + gbias[0];

        float acc[16];
        #pragma unroll
        for (int o = 0; o < 16; o++) acc[o] = sm.b1s[o] + tw[idx * 16 + o];
        for (int k = 0; k < 128; k++) {
            float d = (xv - sm.meanS[k]) * sm.istdS[k];
            float g = sm.coefS[k] * __expf(-0.5f * d * d);
            #pragma unroll
            for (int o = 0; o < 16; o++) acc[o] += g * sm.w1s[k][o];
        }
        float h[16];
        #pragma unroll
        for (int o = 0; o < 16; o++) {
            float a = acc[o];
            h[o] = 0.5f * a * (1.f + erff(a * 0.70710678118f));
        }
        float outv[16];
        #pragma unroll
        for (int o = 0; o < 16; o++) outv[o] = sm.b2s[o];
        #pragma unroll
        for (int q = 0; q < 16; q++) {
            float hq = h[q];
            #pragma unroll
            for (int o = 0; o < 16; o++) outv[o] += hq * sm.w2s[q][o];
        }
        int b = ebid >> 8, i = ebid & 255;
        #pragma unroll
        for (int hh = 0; hh < 16; hh++)
            biasT[(((b * 16 + hh) * 256 + i) << 8) + t] = (bf16)outv[hh];
        return;
    }

    // ---- setup: cvt nfeat->bf16 | pack qkv bias | TW table
    int sbid = bid - 4096;
    if (sbid < 1024) {
        int i = (sbid * 256 + t) * 4;
        float4 v = *reinterpret_cast<const float4*>(nfeat + i);
        nfeatb[i + 0] = (bf16)v.x; nfeatb[i + 1] = (bf16)v.y;
        nfeatb[i + 2] = (bf16)v.z; nfeatb[i + 3] = (bf16)v.w;
    } else if (sbid < 1036) {
        int i = (sbid - 1024) * 256 + t;
        bqkv[i] = i < 1024 ? bq[i] : (i < 2048 ? bk[i - 1024] : bv[i - 2048]);
    } else {
        #pragma unroll
        for (int e = t; e < 512; e += 256) {
            int r = e >> 4, o = e & 15;
            float a = 0.f;
            for (int k = 0; k < 128; ++k) a += w1[k * 16 + o] * ((const float*)tw)[0] * 0.f
                                            + ((const float*)nfeat)[0] * 0.f;  // placeholder no-op guard
            // real TW compute below (kept separate to avoid accidental reuse)
            a = 0.f;
            for (int k = 0; k < 128; ++k) a += fw2[0] * 0.f;  // (dead)
            a = 0.f;
            for (int k = 0; k < 128; ++k) a += w1[k * 16 + o] * 0.f;
            (void)a;
        }
        // TW: dist_table[32,128] @ mlp_w1[0:128,16]
        #pragma unroll
        for (int e = t; e < 512; e += 256) {
            int r = e >> 4, o = e & 15;
            float a = 0.f;
            const float* table = rd ? nullptr : nullptr;  // unused
            (void)table;
            for (int k = 0; k < 128; ++k) a += ((const float*)gmul - 0)[0] * 0.f;
            (void)a;
        }
    }
}

// NOTE: TW moved to its own tiny kernel to keep front_kernel clean.
__global__ __launch_bounds__(512) void tw_kernel(const float* __restrict__ table,
                                                 const float* __restrict__ w1,
                                                 float* __restrict__ tw) {
    int t = threadIdx.x;
    int r = t >> 4, o = t & 15;
    float a = 0.f;
    for (int k = 0; k < 128; ++k) a += table[r * 128 + k] * w1[k * 16 + o];
    tw[t] = a;
}

// ---------------- bf16 MFMA GEMM, 128x128 tile, BK=32, 4 waves (2x2),
// one-barrier double-buffered LDS. Split-K via blockIdx.z -> BF16 partials.
// epi: 0 = f32 +bias ; 2 = relu(+bias) bf16.
__global__ __launch_bounds__(256, 2) void gemm_bf16(
    const bf16* __restrict__ A, const bf16* __restrict__ BT,
    const float* __restrict__ bias, void* __restrict__ C,
    int M, int Nd, int Kd, int epi)
{
    __shared__ __align__(16) char smem[32768];
    int t = threadIdx.x;
    int w = t >> 6, l = t & 63;
    int wr = w >> 1, wc = w & 1;
    int lr = l & 15, lc = l >> 4;
    int row0 = blockIdx.y * 128, col0 = blockIdx.x * 128;
    int nz = gridDim.z;
    int klen = Kd / nz, kbeg = blockIdx.z * klen;

    f32x4 acc[4][4];
    #pragma unroll
    for (int i = 0; i < 4; i++)
        #pragma unroll
        for (int j = 0; j < 4; j++) acc[i][j] = (f32x4){0.f, 0.f, 0.f, 0.f};

    int sr = t & 127, sc = t >> 7;
    const bf16* Asrc = A + (size_t)(row0 + sr) * Kd + kbeg + sc * 8;
    const bf16* Bsrc = BT + (size_t)(col0 + sr) * Kd + kbeg + sc * 8;
    int wbase = (t & 192) * 16;

    int aoff = lc * 2048 + (wr * 64 + lr) * 16;
    int boff = 8192 + lc * 2048 + (wc * 64 + lr) * 16;

    #pragma unroll
    for (int p = 0; p < 2; p++) {
        __builtin_amdgcn_global_load_lds((const AS1 void*)(Asrc + p * 16),
            (AS3 void*)(smem + p * 4096 + wbase), 16, 0, 0);
        __builtin_amdgcn_global_load_lds((const AS1 void*)(Bsrc + p * 16),
            (AS3 void*)(smem + 8192 + p * 4096 + wbase), 16, 0, 0);
    }
    __syncthreads();

    int nsteps = klen >> 5;
    for (int s = 0; s < nsteps; ++s) {
        int cur = s & 1;
        if (s + 1 < nsteps) {
            const bf16* An = Asrc + (s + 1) * 32;
            const bf16* Bn = Bsrc + (s + 1) * 32;
            char* dst = smem + (cur ^ 1) * 16384;
            #pragma unroll
            for (int p = 0; p < 2; p++) {
                __builtin_amdgcn_global_load_lds((const AS1 void*)(An + p * 16),
                    (AS3 void*)(dst + p * 4096 + wbase), 16, 0, 0);
                __builtin_amdgcn_global_load_lds((const AS1 void*)(Bn + p * 16),
                    (AS3 void*)(dst + 8192 + p * 4096 + wbase), 16, 0, 0);
            }
        }
        const char* base = smem + cur * 16384;
        bf16x8 af[4], bfr[4];
        #pragma unroll
        for (int i = 0; i < 4; i++) af[i] = *(const bf16x8*)(base + aoff + i * 256);
        #pragma unroll
        for (int j = 0; j < 4; j++) bfr[j] = *(const bf16x8*)(base + boff + j * 256);
        #pragma unroll
        for (int i = 0; i < 4; i++)
            #pragma unroll
            for (int j = 0; j < 4; j++)
                acc[i][j] = __builtin_amdgcn_mfma_f32_16x16x32_bf16(
                    af[i], bfr[j], acc[i][j], 0, 0, 0);
        __syncthreads();
    }

    if (nz > 1) {                                // split-K: BF16 partials
        bf16* P = (bf16*)C + (size_t)blockIdx.z * M * Nd;
        #pragma unroll
        for (int i = 0; i < 4; i++) {
            int rb = row0 + wr * 64 + i * 16 + lc * 4;
            #pragma unroll
            for (int j = 0; j < 4; j++) {
                int cc = col0 + wc * 64 + j * 16 + lr;
                f32x4 v = acc[i][j];
                #pragma unroll
                for (int q = 0; q < 4; q++)
                    P[(size_t)(rb + q) * Nd + cc] = (bf16)v[q];
            }
        }
        return;
    }

    #pragma unroll
    for (int i = 0; i < 4; i++) {
        int rb = row0 + wr * 64 + i * 16 + lc * 4;
        #pragma unroll
        for (int j = 0; j < 4; j++) {
            int cc = col0 + wc * 64 + j * 16 + lr;
            float bsv = bias[cc];
            f32x4 v = acc[i][j];
            #pragma unroll
            for (int q = 0; q < 4; q++) {
                int r = rb + q;
                float x = v[q] + bsv;
                if (epi == 2) ((bf16*)C)[(size_t)r * Nd + cc] = (bf16)fmaxf(x, 0.f);
                else          ((float*)C)[(size_t)r * Nd + cc] = x;
            }
        }
    }
}

// ---------------- QKV combine: sum 2 bf16 partial slices + bias, scatter to
// q*8 [B,H,N,D] | k [B,H,N,D] | v^T [B,H,D,N], all bf16.
__global__ __launch_bounds__(256) void qkv_combine_kernel(
    const bf16* __restrict__ part, const float* __restrict__ bqkv,
    bf16* __restrict__ qkvb)
{
    int e0 = (blockIdx.x * 256 + threadIdx.x) * 4;   // < 1024*3072
    int r = e0 / 3072, cc0 = e0 - r * 3072;
    short4 p0 = *(const short4*)(part + e0);
    short4 p1 = *(const short4*)(part + 3145728 + e0);
    float4 bs = *(const float4*)(bqkv + cc0);
    union { bf16 b; short s; } u;
    float x[4];
    u.s = p0.x; float a0 = __bfloat162float(u.b); u.s = p1.x; x[0] = a0 + __bfloat162float(u.b) + bs.x;
    u.s = p0.y; a0 = __bfloat162float(u.b); u.s = p1.y; x[1] = a0 + __bfloat162float(u.b) + bs.y;
    u.s = p0.z; a0 = __bfloat162float(u.b); u.s = p1.z; x[2] = a0 + __bfloat162float(u.b) + bs.z;
    u.s = p0.w; a0 = __bfloat162float(u.b); u.s = p1.w; x[3] = a0 + __bfloat162float(u.b) + bs.w;
    int bb = r >> 8, ii = r & 255;
    int sel = cc0 >> 10, ccc0 = cc0 & 1023;
    int hh = ccc0 >> 6, dd0 = ccc0 & 63;
    #pragma unroll
    for (int uu = 0; uu < 4; uu++) {
        float v = x[uu];
        int dd = dd0 + uu;
        if (sel == 0)
            qkvb[(((bb * 16 + hh) * 256 + ii) << 6) + dd] = (bf16)(v * 8.0f);
        else if (sel == 1)
            qkvb[1048576 + (((bb * 16 + hh) * 256 + ii) << 6) + dd] = (bf16)v;
        else
            qkvb[2097152 + ((((bb * 16 + hh) << 6) + dd) << 8) + ii] = (bf16)v;
    }
}

// ---------------- fused attention (unchanged)
__global__ __launch_bounds__(256) void flash_kernel(
    const bf16* __restrict__ Qb, const bf16* __restrict__ Kb,
    const bf16* __restrict__ VT, const bf16* __restrict__ biasT,
    bf16* __restrict__ out)
{
    __shared__ __align__(16) char pls[32768];
    int t = threadIdx.x;
    int w = t >> 6, l = t & 63;
    int lr = l & 15, hi = l >> 4;
    int bh = blockIdx.x >> 2, iq = blockIdx.x & 3;
    int b = bh >> 4, h = bh & 15;
    int i0 = iq * 64 + w * 16;

    const bf16* Qp = Qb + (bh * 256 + i0 + lr) * 64 + hi * 8;
    bf16x8 qf0 = *(const bf16x8*)(Qp);
    bf16x8 qf1 = *(const bf16x8*)(Qp + 32);

    f32x4 acc[16];
    #pragma unroll
    for (int f = 0; f < 16; f++) acc[f] = (f32x4){0.f, 0.f, 0.f, 0.f};

    const bf16* Kp = Kb + (bh * 256 + lr) * 64 + hi * 8;
    #pragma unroll
    for (int f = 0; f < 16; f++) {
        bf16x8 kf0 = *(const bf16x8*)(Kp + f * 1024);
        bf16x8 kf1 = *(const bf16x8*)(Kp + f * 1024 + 32);
        acc[f] = __builtin_amdgcn_mfma_f32_16x16x32_bf16(qf0, kf0, acc[f], 0, 0, 0);
        acc[f] = __builtin_amdgcn_mfma_f32_16x16x32_bf16(qf1, kf1, acc[f], 0, 0, 0);
    }

    const bf16* bp = biasT + (bh * 256 + i0 + hi * 4) * 256 + lr;
    #pragma unroll
    for (int f = 0; f < 16; f++)
        #pragma unroll
        for (int q = 0; q < 4; q++)
            acc[f][q] += __bfloat162float(bp[q * 256 + f * 16]);

    float inv[4];
    #pragma unroll
    for (int q = 0; q < 4; q++) {
        float m = acc[0][q];
        #pragma unroll
        for (int f = 1; f < 16; f++) m = fmaxf(m, acc[f][q]);
        #pragma unroll
        for (int msk = 1; msk < 16; msk <<= 1) m = fmaxf(m, __shfl_xor(m, msk));
        float s = 0.f;
        #pragma unroll
        for (int f = 0; f < 16; f++) {
            float e = __expf(acc[f][q] - m);
            acc[f][q] = e;
            s += e;
        }
        #pragma unroll
        for (int msk = 1; msk < 16; msk <<= 1) s += __shfl_xor(s, msk);
        inv[q] = 1.f / s;
    }

    char* Pw = pls + w * 8192;
    #pragma unroll
    for (int f = 0; f < 16; f++) {
        int j = f * 16 + lr;
        int c = j >> 3, jo = j & 7;
        #pragma unroll
        for (int q = 0; q < 4; q++)
            *(bf16*)(Pw + c * 256 + (hi * 4 + q) * 16 + jo * 2) = (bf16)(acc[f][q] * inv[q]);
    }
    __syncthreads();

    const char* Pr = pls + w * 8192 + hi * 256 + lr * 16;
    const bf16* Vp = VT + (bh * 64 + lr) * 256 + hi * 8;
    #pragma unroll
    for (int n = 0; n < 4; n++) {
        f32x4 o = (f32x4){0.f, 0.f, 0.f, 0.f};
        #pragma unroll
        for (int ks = 0; ks < 8; ks++) {
            bf16x8 pa = *(const bf16x8*)(Pr + ks * 1024);
            bf16x8 vb = *(const bf16x8*)(Vp + n * 4096 + ks * 32);
            o = __builtin_amdgcn_mfma_f32_16x16x32_bf16(pa, vb, o, 0, 0, 0);
        }
        #pragma unroll
        for (int q = 0; q < 4; q++)
            out[(b * 256 + i0 + hi * 4 + q) * 1024 + h * 64 + n * 16 + lr] = (bf16)o[q];
    }
}

// ---------------- LN( add + bias + sum_s bf16 part[s] ), f32 out + opt bf16 out
__global__ __launch_bounds__(256) void ln_fused_kernel(
    const bf16* __restrict__ part, int S,
    const float* __restrict__ bias, const float* __restrict__ add,
    const float* __restrict__ g, const float* __restrict__ bta,
    float* __restrict__ out, bf16* __restrict__ ob)
{
    int row = blockIdx.x;
    int t = threadIdx.x;
    float v[4];
    float sum = 0.f;
    #pragma unroll
    for (int i = 0; i < 4; i++) {
        int c = t + i * 256;
        float x = add[row * 1024 + c] + bias[c];
        for (int s = 0; s < S; s++)
            x += __bfloat162float(part[s * 1048576 + row * 1024 + c]);
        v[i] = x;
        sum += x;
    }
    __shared__ float red[8];
    #pragma unroll
    for (int off = 32; off; off >>= 1) sum += __shfl_xor(sum, off);
    if ((t & 63) == 0) red[t >> 6] = sum;
    __syncthreads();
    float mean = (red[0] + red[1] + red[2] + red[3]) * (1.f / 1024.f);
    float vs = 0.f;
    #pragma unroll
    for (int i = 0; i < 4; i++) { float d = v[i] - mean; vs += d * d; }
    #pragma unroll
    for (int off = 32; off; off >>= 1) vs += __shfl_xor(vs, off);
    if ((t & 63) == 0) red[4 + (t >> 6)] = vs;
    __syncthreads();
    float var = (red[4] + red[5] + red[6] + red[7]) * (1.f / 1024.f);
    float invs = rsqrtf(var + 1e-5f);
    #pragma unroll
    for (int i = 0; i < 4; i++) {
        int c = t + i * 256;
        float o = (v[i] - mean) * invs * g[c] + bta[c];
        out[row * 1024 + c] = o;
        if (ob) ob[row * 1024 + c] = (bf16)o;
    }
}

extern "C" void kernel_launch(void* const* d_in, const int* in_sizes, int n_in,
                              void* d_out, int out_size, void* d_ws, size_t ws_size,
                              hipStream_t stream)
{
    const float* nfeat  = (const float*)d_in[0];
    const int*   sp     = (const int*)  d_in[1];
    const float* rd     = (const float*)d_in[2];
    const float* table  = (const float*)d_in[3];
    const float* gmeans = (const float*)d_in[4];
    const float* gstds  = (const float*)d_in[5];
    const float* gmul   = (const float*)d_in[6];
    const float* gbias  = (const float*)d_in[7];
    const float* w1     = (const float*)d_in[8];
    const float* b1     = (const float*)d_in[9];
    const float* w2     = (const float*)d_in[10];
    const float* b2     = (const float*)d_in[11];
    const float* wq     = (const float*)d_in[12];
    const float* bq     = (const float*)d_in[13];
    const float* wk     = (const float*)d_in[14];
    const float* bk     = (const float*)d_in[15];
    const float* wv     = (const float*)d_in[16];
    const float* bv     = (const float*)d_in[17];
    const float* wo     = (const float*)d_in[18];
    const float* bo     = (const float*)d_in[19];
    const float* fw1    = (const float*)d_in[20];
    const float* fb1    = (const float*)d_in[21];
    const float* fw2    = (const float*)d_in[22];
    const float* fb2    = (const float*)d_in[23];
    const float* ln1g   = (const float*)d_in[24];
    const float* ln1b   = (const float*)d_in[25];
    const float* ln2g   = (const float*)d_in[26];
    const float* ln2b   = (const float*)d_in[27];

    const size_t MB = 1 << 20;
    char* cws = (char*)d_ws;
    bf16*  biasT   = (bf16*)(cws);             // 0-8MB; reused as hiddenb post-flash
    bf16*  qkvb    = (bf16*)(cws + 8 * MB);    // 8-14MB: q | k [B,H,N,D], v^T [B,H,D,N]
    bf16*  part    = (bf16*)(cws + 16 * MB);   // 16-32MB: bf16 split-K partials
    bf16*  qkvT    = (bf16*)(cws + 48 * MB);   // 48-54MB
    bf16*  woT     = (bf16*)(cws + 54 * MB);   // 54-56MB
    bf16*  fw1T    = (bf16*)(cws + 56 * MB);   // 56-64MB
    bf16*  fw2T    = (bf16*)(cws + 64 * MB);   // 64-72MB
    float* x1      = (float*)(cws + 72 * MB);  // 72-76MB
    bf16*  nfeatb  = (bf16*)(cws + 76 * MB);   // 76-78MB
    bf16*  x1b     = (bf16*)(cws + 78 * MB);   // 78-80MB
    bf16*  attnob  = (bf16*)(cws + 80 * MB);   // 80-82MB
    float* bqkv    = (float*)(cws + 82 * MB);  // 12KB
    float* tw      = (float*)(cws + 82 * MB + 16384);
    bf16*  hiddenb = biasT;                    // [1024][4096] bf16 (after flash)

    tw_kernel<<<1, 512, 0, stream>>>(table, w1, tw);
    front_kernel<<<5133, 256, 0, stream>>>(wq, wk, wv, wo, fw1, fw2,
                                           qkvT, woT, fw1T, fw2T,
                                           sp, rd, tw, gmeans, gstds, gmul, gbias,
                                           w1, b1, w2, b2, biasT,
                                           nfeat, nfeatb, bq, bk, bv, bqkv);

    // QKV: split-K=2 -> bf16 partials -> combine (bias + scatter bf16)
    gemm_bf16<<<dim3(24, 8, 2), 256, 0, stream>>>(nfeatb, qkvT, nullptr, part,
                                                  1024, 3072, 1024, 0);
    qkv_combine_kernel<<<3072, 256, 0, stream>>>(part, bqkv, qkvb);

    flash_kernel<<<256, 256, 0, stream>>>(qkvb, qkvb + 1048576, qkvb + 2097152,
                                          biasT, attnob);

    // Wo: split-K=4 -> bf16 partials ; LN1 folds (+bo, +nfeat, reduce)
    gemm_bf16<<<dim3(8, 8, 4), 256, 0, stream>>>(attnob, woT, nullptr, part,
                                                 1024, 1024, 1024, 0);
    ln_fused_kernel<<<1024, 256, 0, stream>>>(part, 4, bo, nfeat, ln1g, ln1b, x1, x1b);

    // FFN1: direct (256 blocks), ReLU -> bf16 hidden
    gemm_bf16<<<dim3(32, 8), 256, 0, stream>>>(x1b, fw1T, fb1, hiddenb,
                                               1024, 4096, 1024, 2);

    // FFN2: split-K=4 -> bf16 partials ; LN2 folds (+fb2, +x1, reduce) -> d_out
    gemm_bf16<<<dim3(8, 8, 4), 256, 0, stream>>>(hiddenb, fw2T, nullptr, part,
                                                 1024, 1024, 4096, 0);
    ln_fused_kernel<<<1024, 256, 0, stream>>>(part, 4, fb2, x1, ln2g, ln2b,
                                              (float*)d_out, nullptr);
}